// Round 12
// baseline (1621.755 us; speedup 1.0000x reference)
//
#include <hip/hip_runtime.h>
#include <stdint.h>

#define BATCH   8192
#define IN_DIM  256
#define HID_DIM 16384
#define OUT_DIM 256

#define SELCAPF 2048

typedef __attribute__((ext_vector_type(4))) float f32x4;
typedef __attribute__((ext_vector_type(2))) float f32x2;

__device__ __forceinline__ void load_lds_16B(const void* g, void* l) {
  __builtin_amdgcn_global_load_lds(
      (const __attribute__((address_space(1))) unsigned int*)g,
      (__attribute__((address_space(3))) unsigned int*)l, 16, 0, 0);
}
__device__ __forceinline__ float bf16u_to_f(unsigned short u) {
  return __uint_as_float(((unsigned)u) << 16);
}
__device__ __forceinline__ unsigned short f_to_bf16_rne(float f) {
  unsigned u = __float_as_uint(f);
  u += 0x7fffu + ((u >> 16) & 1u);
  return (unsigned short)(u >> 16);
}
__device__ __forceinline__ int read_k(const int* kptr) {
  int k = kptr[0];
  if (k <= 0 || k > 100000000) {
    float kf = __int_as_float(k);
    if (kf >= 1.f && kf <= 16384.f) k = (int)kf;
  }
  if (k < 1) k = 1;
  if (k > HID_DIM) k = HID_DIM;
  return k;
}
__device__ __forceinline__ f32x2 fma2(f32x2 a, f32x2 b, f32x2 c) {
#if __has_builtin(__builtin_elementwise_fma)
  return __builtin_elementwise_fma(a, b, c);   // v_pk_fma_f32: two independent IEEE FMAs
#else
  f32x2 r; r[0] = fmaf(a[0], b[0], c[0]); r[1] = fmaf(a[1], b[1], c[1]); return r;
#endif
}

// ---------------- dec_w (256 x 16384 fp32) -> dec_wT (16384 x 256 bf16) ----------------
__global__ __launch_bounds__(256) void k_transb(const float* __restrict__ dec_w,
                                                unsigned short* __restrict__ decT) {
  __shared__ float tile[32][33];
  int j0 = blockIdx.x * 32, o0 = blockIdx.y * 32;
  int tx = threadIdx.x & 31, ty = threadIdx.x >> 5;
#pragma unroll
  for (int rr = 0; rr < 4; rr++)
    tile[ty + rr * 8][tx] = dec_w[(size_t)(o0 + ty + rr * 8) * HID_DIM + (j0 + tx)];
  __syncthreads();
#pragma unroll
  for (int rr = 0; rr < 4; rr++)
    decT[(size_t)(j0 + ty + rr * 8) * OUT_DIM + (o0 + tx)] = f_to_bf16_rne(tile[tx][ty + rr * 8]);
}

// ---- blocked transpose: src[R x 256] -> dst[R/128][256][128] (values exact; layout only) ----
__global__ __launch_bounds__(256) void k_transblk(const float* __restrict__ src,
                                                  float* __restrict__ dst) {
  __shared__ float tile[32][33];
  const int r0 = blockIdx.x * 32, k0 = blockIdx.y * 32;
  const int tx = threadIdx.x & 31, ty = threadIdx.x >> 5;
#pragma unroll
  for (int rr = 0; rr < 4; rr++)
    tile[ty + rr * 8][tx] = src[(size_t)(r0 + ty + rr * 8) * IN_DIM + (k0 + tx)];
  __syncthreads();
  const int blk = r0 >> 7, rin = r0 & 127;
#pragma unroll
  for (int rr = 0; rr < 4; rr++) {
    const int kk = k0 + ty + rr * 8;
    dst[((size_t)blk * IN_DIM + kk) * 128 + rin + tx] = tile[tx][ty + rr * 8];
  }
}

// ---------------- GEMM1 (packed fp32, DMA staging): hid = relu(x @ enc_w^T + enc_b) ---------
// Per-element fp sequence BIT-IDENTICAL to R3/R6/R7/R9/R10: acc=0; ascending-k IEEE fma
// chain; h = acc + enc_b; relu. ONLY change vs R10: a-operand splats are expressed as
// direct shufflevector(av, av, i, i) so the backend can fold them into v_pk_fma_f32 op_sel
// (no v_mov). Per-component arithmetic identical => bit-identical hidden values.
__global__ __launch_bounds__(256, 4) void k_gemm_pk2(const float* __restrict__ XT,
                                                     const float* __restrict__ WT,
                                                     const float* __restrict__ encb,
                                                     float* __restrict__ hid) {
  __shared__ __align__(16) float As[32 * 128];   // [k][m], 16 KB
  __shared__ __align__(16) float Bs[32 * 128];   // [k][n]
  const int bn = blockIdx.x, bm = blockIdx.y;
  const int t = threadIdx.x, w = t >> 6, lane = t & 63;
  const int tx = t & 15, ty = t >> 4;            // 16x16 threads, 8x8 outputs each

  f32x2 acc[8][4] = {};                          // [i][j-pair]; col = tx*8 + jp*2 + {0,1}

  const float* Abase = XT + (size_t)bm * (IN_DIM * 128);
  const float* Bbase = WT + (size_t)bn * (IN_DIM * 128);

  for (int k0 = 0; k0 < IN_DIM; k0 += 32) {
    // Stage 16 KB per array: 16 wave-ops of 1 KB each; lane i moves bytes [i*16, i*16+16).
#pragma unroll
    for (int o = 0; o < 4; o++) {
      const int i = w * 4 + o;
      load_lds_16B(Abase + k0 * 128 + i * 256 + lane * 4, &As[i * 256]);
      load_lds_16B(Bbase + k0 * 128 + i * 256 + lane * 4, &Bs[i * 256]);
    }
    __syncthreads();
#pragma unroll 8
    for (int kk = 0; kk < 32; kk++) {            // ascending k: preserves fp order
      const f32x4 av0 = *(const f32x4*)&As[kk * 128 + ty * 8];
      const f32x4 av1 = *(const f32x4*)&As[kk * 128 + ty * 8 + 4];
      const f32x4 bv0 = *(const f32x4*)&Bs[kk * 128 + tx * 8];
      const f32x4 bv1 = *(const f32x4*)&Bs[kk * 128 + tx * 8 + 4];
      f32x2 a2[8], b2[4];
      a2[0] = __builtin_shufflevector(av0, av0, 0, 0);   // splat -> op_sel-foldable
      a2[1] = __builtin_shufflevector(av0, av0, 1, 1);
      a2[2] = __builtin_shufflevector(av0, av0, 2, 2);
      a2[3] = __builtin_shufflevector(av0, av0, 3, 3);
      a2[4] = __builtin_shufflevector(av1, av1, 0, 0);
      a2[5] = __builtin_shufflevector(av1, av1, 1, 1);
      a2[6] = __builtin_shufflevector(av1, av1, 2, 2);
      a2[7] = __builtin_shufflevector(av1, av1, 3, 3);
      b2[0] = __builtin_shufflevector(bv0, bv0, 0, 1);
      b2[1] = __builtin_shufflevector(bv0, bv0, 2, 3);
      b2[2] = __builtin_shufflevector(bv1, bv1, 0, 1);
      b2[3] = __builtin_shufflevector(bv1, bv1, 2, 3);
#pragma unroll
      for (int i = 0; i < 8; i++)
#pragma unroll
        for (int j = 0; j < 4; j++)
          acc[i][j] = fma2(a2[i], b2[j], acc[i][j]);
    }
    __syncthreads();
  }

#pragma unroll
  for (int i = 0; i < 8; i++) {
    const int m = bm * 128 + ty * 8 + i;
    float o[8];
#pragma unroll
    for (int j = 0; j < 4; j++) {
      const float h0 = acc[i][j][0] + encb[bn * 128 + tx * 8 + j * 2];
      const float h1 = acc[i][j][1] + encb[bn * 128 + tx * 8 + j * 2 + 1];
      o[j * 2]     = (h0 > 0.f) ? h0 : 0.f;
      o[j * 2 + 1] = (h1 > 0.f) ? h1 : 0.f;
    }
    float* dst = &hid[(size_t)m * HID_DIM + bn * 128 + tx * 8];
    *(float4*)dst = *(float4*)&o[0];
    *(float4*)(dst + 4) = *(float4*)&o[4];
  }
}

// ---------------- topk3 (R6/R10 verbatim, proven): reg-resident row, full 32-bit radix --------
// Selection rule: T = exact bits of k-th largest stored value; keep iff bits >= T.
__global__ __launch_bounds__(256) void k_topk3(const unsigned short* __restrict__ decTb,
                                               const float* __restrict__ decb,
                                               const int* __restrict__ kptr,
                                               float* __restrict__ out,
                                               float* __restrict__ hid) {
  __shared__ unsigned hist[8][257];
  __shared__ unsigned cums[257];
  __shared__ float selV[SELCAPF];
  __shared__ unsigned short selI[SELCAPF];
  __shared__ unsigned s_selcnt, s_b, s_need;
  __shared__ int s_keepall;

  const int r = blockIdx.x, t = threadIdx.x;
  float* hrow = hid + (size_t)r * HID_DIM;
  const int k = read_k(kptr);

  // Row -> registers (the ONLY global read of the row).
  f32x4 row[16];
#pragma unroll
  for (int c = 0; c < 16; c++) row[c] = *(const f32x4*)&hrow[(c * 256 + t) * 4];

  for (int i = t; i < 8 * 257; i += 256) ((unsigned*)hist)[i] = 0u;
  if (t == 0) { s_selcnt = 0; s_keepall = 0; }
  __syncthreads();

  // Radix pass 0: top byte (post-relu => sign bit 0); skip byte==0.
#pragma unroll
  for (int c = 0; c < 16; c++)
#pragma unroll
    for (int e = 0; e < 4; e++) {
      const unsigned b = __float_as_uint(row[c][e]) >> 24;
      if (b) atomicAdd(&hist[t & 7][b], 1u);
    }
  __syncthreads();
  { unsigned s = 0;
#pragma unroll
    for (int cpy = 0; cpy < 8; cpy++) s += hist[cpy][t];
    cums[t] = s; }
  __syncthreads();
  for (int off = 1; off < 256; off <<= 1) {   // suffix scan: cums[t] = #{top-byte >= t}
    const unsigned v = cums[t];
    const unsigned a = (t + off < 256) ? cums[t + off] : 0u;
    __syncthreads();
    cums[t] = v + a;
    __syncthreads();
  }
  if (t == 0 && cums[1] < (unsigned)k) s_keepall = 1;  // k-th is (sub)zero -> keep all
  if (t >= 1) {
    const unsigned incl = cums[t], excl = (t < 255) ? cums[t + 1] : 0u;
    if (incl >= (unsigned)k && excl < (unsigned)k) { s_b = (unsigned)t; s_need = (unsigned)k - excl; }
  }
  __syncthreads();

  unsigned prefix = 0;
  const int keepall = s_keepall;
  if (!keepall) {
    prefix = s_b << 24;
    unsigned need = s_need;
    for (int pass = 0; pass < 3; pass++) {     // shifts 16, 8, 0 -> full 32-bit T
      const int shift = 16 - pass * 8;
      for (int i = t; i < 8 * 257; i += 256) ((unsigned*)hist)[i] = 0u;
      __syncthreads();
      const unsigned pfx = prefix;
      const int pshift = shift + 8;
#pragma unroll
      for (int c = 0; c < 16; c++)
#pragma unroll
        for (int e = 0; e < 4; e++) {
          const unsigned bits = __float_as_uint(row[c][e]);
          if ((bits >> pshift) == (pfx >> pshift))
            atomicAdd(&hist[t & 7][(bits >> shift) & 255u], 1u);
        }
      __syncthreads();
      { unsigned s = 0;
#pragma unroll
        for (int cpy = 0; cpy < 8; cpy++) s += hist[cpy][t];
        cums[t] = s; }
      __syncthreads();
      for (int off = 1; off < 256; off <<= 1) {
        const unsigned v = cums[t];
        const unsigned a = (t + off < 256) ? cums[t + off] : 0u;
        __syncthreads();
        cums[t] = v + a;
        __syncthreads();
      }
      { const unsigned incl = cums[t], excl = (t < 255) ? cums[t + 1] : 0u;
        if (incl >= need && excl < need) { s_b = (unsigned)t; s_need = need - excl; } }
      __syncthreads();
      prefix |= s_b << shift;
      need = s_need;
      __syncthreads();
    }
  }
  const unsigned T = prefix;   // exact bits of the k-th largest value (ties kept via >=)

  // Mask + write hidden_post + gather survivors (all from registers).
#pragma unroll
  for (int c = 0; c < 16; c++) {
    const int base = (c * 256 + t) * 4;
    f32x4 o;
#pragma unroll
    for (int e = 0; e < 4; e++) {
      const float v = row[c][e];
      const unsigned bits = __float_as_uint(v);
      const bool keep = keepall || (bits >= T);
      o[e] = keep ? v : 0.f;
      if (keep && bits != 0u) {
        const unsigned p = atomicAdd(&s_selcnt, 1u);
        if (p < SELCAPF) { selV[p] = v; selI[p] = (unsigned short)(base + e); }
      }
    }
    *(f32x4*)&hrow[base] = o;
  }
  __syncthreads();

  // Fused sparse decode: out[r][t] = dec_b[t] + sum_s v_s * dec_w[t][j_s]
  const unsigned nsel = s_selcnt;
  float a0 = decb[t], a1 = 0.f, a2 = 0.f, a3 = 0.f;
  if (nsel <= SELCAPF) {
    unsigned s = 0;
    for (; s + 4 <= nsel; s += 4) {
      a0 += selV[s + 0] * bf16u_to_f(decTb[(size_t)selI[s + 0] * OUT_DIM + t]);
      a1 += selV[s + 1] * bf16u_to_f(decTb[(size_t)selI[s + 1] * OUT_DIM + t]);
      a2 += selV[s + 2] * bf16u_to_f(decTb[(size_t)selI[s + 2] * OUT_DIM + t]);
      a3 += selV[s + 3] * bf16u_to_f(decTb[(size_t)selI[s + 3] * OUT_DIM + t]);
    }
    for (; s < nsel; s++)
      a0 += selV[s] * bf16u_to_f(decTb[(size_t)selI[s] * OUT_DIM + t]);
  } else {
    for (int j = 0; j < HID_DIM; j++) {        // rare huge-k fallback (row already masked)
      const float hv = hrow[j];
      if (hv != 0.f) a0 += hv * bf16u_to_f(decTb[(size_t)j * OUT_DIM + t]);
    }
  }
  out[(size_t)r * OUT_DIM + t] = (a0 + a1) + (a2 + a3);
}

// ======================= fallback (small ws): R7's proven kernels =======================
__global__ __launch_bounds__(256, 4) void k_gemm_pk(const float* __restrict__ X,
                                                    const float* __restrict__ W,
                                                    const float* __restrict__ encb,
                                                    float* __restrict__ hid) {
  __shared__ float As[32][132];
  __shared__ float Bs[32][132];
  const int bn = blockIdx.x, bm = blockIdx.y;
  const int t = threadIdx.x;
  const int tx = t & 15, ty = t >> 4;
  const int sr = t & 127, sh = t >> 7;
  f32x2 acc[8][4] = {};
  const float* Ab = X + (size_t)(bm * 128) * IN_DIM;
  const float* Bb = W + (size_t)(bn * 128) * IN_DIM;
  for (int k0 = 0; k0 < IN_DIM; k0 += 32) {
#pragma unroll
    for (int q = 0; q < 4; q++) {
      const int ko = sh * 16 + q * 4;
      const float4 av = *(const float4*)&Ab[(size_t)sr * IN_DIM + k0 + ko];
      As[ko + 0][sr] = av.x; As[ko + 1][sr] = av.y;
      As[ko + 2][sr] = av.z; As[ko + 3][sr] = av.w;
      const float4 bv = *(const float4*)&Bb[(size_t)sr * IN_DIM + k0 + ko];
      Bs[ko + 0][sr] = bv.x; Bs[ko + 1][sr] = bv.y;
      Bs[ko + 2][sr] = bv.z; Bs[ko + 3][sr] = bv.w;
    }
    __syncthreads();
#pragma unroll 8
    for (int kk = 0; kk < 32; kk++) {
      const f32x4 av0 = *(const f32x4*)&As[kk][ty * 8];
      const f32x4 av1 = *(const f32x4*)&As[kk][ty * 8 + 4];
      const f32x4 bv0 = *(const f32x4*)&Bs[kk][tx * 8];
      const f32x4 bv1 = *(const f32x4*)&Bs[kk][tx * 8 + 4];
      f32x2 b2[4];
      b2[0] = __builtin_shufflevector(bv0, bv0, 0, 1);
      b2[1] = __builtin_shufflevector(bv0, bv0, 2, 3);
      b2[2] = __builtin_shufflevector(bv1, bv1, 0, 1);
      b2[3] = __builtin_shufflevector(bv1, bv1, 2, 3);
#pragma unroll
      for (int i = 0; i < 8; i++) {
        const float asc = (i < 4) ? av0[i & 3] : av1[i & 3];
        f32x2 ai; ai[0] = asc; ai[1] = asc;
#pragma unroll
        for (int j = 0; j < 4; j++) acc[i][j] = fma2(ai, b2[j], acc[i][j]);
      }
    }
    __syncthreads();
  }
#pragma unroll
  for (int i = 0; i < 8; i++) {
    const int m = bm * 128 + ty * 8 + i;
    float o[8];
#pragma unroll
    for (int j = 0; j < 4; j++) {
      const float h0 = acc[i][j][0] + encb[bn * 128 + tx * 8 + j * 2];
      const float h1 = acc[i][j][1] + encb[bn * 128 + tx * 8 + j * 2 + 1];
      o[j * 2] = (h0 > 0.f) ? h0 : 0.f;
      o[j * 2 + 1] = (h1 > 0.f) ? h1 : 0.f;
    }
    float* dst = &hid[(size_t)m * HID_DIM + bn * 128 + tx * 8];
    *(float4*)dst = *(float4*)&o[0];
    *(float4*)(dst + 4) = *(float4*)&o[4];
  }
}

__global__ __launch_bounds__(256) void k_topkf(const float* __restrict__ dec,
                                               const float* __restrict__ decb,
                                               const int* __restrict__ kptr,
                                               float* __restrict__ out,
                                               float* __restrict__ hid) {
  __shared__ unsigned hist[8][257];
  __shared__ unsigned tot[256];
  __shared__ float selV[SELCAPF];
  __shared__ unsigned short selI[SELCAPF];
  __shared__ unsigned s_selcnt, s_need, s_pref, s_byte;
  __shared__ int s_keepall;
  const int r = blockIdx.x, t = threadIdx.x;
  float* hrow = hid + (size_t)r * HID_DIM;
  const int k = read_k(kptr);
  for (int i = t; i < 8 * 257; i += 256) ((unsigned*)hist)[i] = 0u;
  if (t == 0) { s_selcnt = 0; s_keepall = 0; s_pref = 0; }
  __syncthreads();
#pragma unroll
  for (int c = 0; c < 16; c++) {
    const f32x4 v = *(const f32x4*)&hrow[(c * 256 + t) * 4];
#pragma unroll
    for (int e = 0; e < 4; e++) {
      const unsigned b = __float_as_uint(v[e]) >> 24;
      if (b) atomicAdd(&hist[t & 7][b], 1u);
    }
  }
  __syncthreads();
  { unsigned s = 0;
#pragma unroll
    for (int c = 0; c < 8; c++) s += hist[c][t];
    tot[t] = s; }
  __syncthreads();
  if (t == 0) {
    unsigned cum = 0; int b1 = -1; unsigned need = 0;
    for (int b = 255; b >= 1; b--) {
      const unsigned c = tot[b];
      if (cum + c >= (unsigned)k) { b1 = b; need = (unsigned)k - cum; break; }
      cum += c;
    }
    if (b1 < 0) s_keepall = 1;
    else { s_pref = ((unsigned)b1) << 24; s_need = need; }
  }
  __syncthreads();
  if (!s_keepall) {
    for (int pass = 1; pass <= 3; pass++) {
      const int shift = 24 - pass * 8;
      tot[t] = 0;
      __syncthreads();
      const unsigned prefhi = s_pref >> (shift + 8);
#pragma unroll
      for (int c = 0; c < 16; c++) {
        const f32x4 v = *(const f32x4*)&hrow[(c * 256 + t) * 4];
#pragma unroll
        for (int e = 0; e < 4; e++) {
          const unsigned bits = __float_as_uint(v[e]);
          if ((bits >> (shift + 8)) == prefhi) atomicAdd(&tot[(bits >> shift) & 255u], 1u);
        }
      }
      __syncthreads();
      if (t == 0) {
        unsigned cum = 0; const unsigned need = s_need;
        for (int b = 255; b >= 0; b--) {
          const unsigned c = tot[b];
          if (cum + c >= need) { s_byte = (unsigned)b; s_need = need - cum; break; }
          cum += c;
        }
        s_pref |= s_byte << shift;
      }
      __syncthreads();
    }
  }
  const int keepall = s_keepall;
  const unsigned T = s_pref;
#pragma unroll
  for (int c = 0; c < 16; c++) {
    const int base = (c * 256 + t) * 4;
    const f32x4 v = *(const f32x4*)&hrow[base];
    f32x4 o;
#pragma unroll
    for (int e = 0; e < 4; e++) {
      const unsigned bits = __float_as_uint(v[e]);
      const bool keep = keepall || (bits >= T);
      o[e] = keep ? v[e] : 0.f;
      if (keep && bits != 0u) {
        const unsigned p = atomicAdd(&s_selcnt, 1u);
        if (p < SELCAPF) { selV[p] = v[e]; selI[p] = (unsigned short)(base + e); }
      }
    }
    *(f32x4*)&hrow[base] = o;
  }
  __syncthreads();
  const unsigned nsel = s_selcnt;
  float a0 = decb[t], a1 = 0.f, a2 = 0.f, a3 = 0.f;
  if (nsel <= SELCAPF) {
    unsigned s = 0;
    for (; s + 4 <= nsel; s += 4) {
#pragma unroll
      for (int u = 0; u < 4; u++) {
        const unsigned idx = selI[s + u];
        (u == 0 ? a0 : u == 1 ? a1 : u == 2 ? a2 : a3) += selV[s + u] * dec[(size_t)t * HID_DIM + idx];
      }
    }
    for (; s < nsel; s++)
      a0 += selV[s] * dec[(size_t)t * HID_DIM + selI[s]];
  } else {
    for (int j = 0; j < HID_DIM; j++) {
      const float hv = hrow[j];
      if (hv != 0.f) a0 += hv * dec[(size_t)t * HID_DIM + j];
    }
  }
  out[(size_t)r * OUT_DIM + t] = (a0 + a1) + (a2 + a3);
}

extern "C" void kernel_launch(void* const* d_in, const int* in_sizes, int n_in,
                              void* d_out, int out_size, void* d_ws, size_t ws_size,
                              hipStream_t stream) {
  // Order remap (dict vs alphabetical), by size signature — proven in R3-R11.
  int ix = 0, iew = 1, ieb = 2, idw = 3, idb = 4, ik = 5;
  if (n_in >= 6 && in_sizes[0] == OUT_DIM && in_sizes[5] == BATCH * IN_DIM) {
    idb = 0; idw = 1; ieb = 2; iew = 3; ik = 4; ix = 5;
  }
  const float* x     = (const float*)d_in[ix];
  const float* enc_w = (const float*)d_in[iew];
  const float* enc_b = (const float*)d_in[ieb];
  const float* dec_w = (const float*)d_in[idw];
  const float* dec_b = (const float*)d_in[idb];
  const int*   kptr  = (const int*)d_in[ik];

  float* out = (float*)d_out;
  float* hid = out + (size_t)BATCH * OUT_DIM;

  const size_t B_decT = (size_t)HID_DIM * OUT_DIM * 2;   // 8 MiB
  const size_t B_XT   = (size_t)BATCH * IN_DIM * 4;      // 8 MiB
  const size_t B_WT   = (size_t)HID_DIM * IN_DIM * 4;    // 16 MiB
  const size_t need = 64 + B_decT + B_XT + B_WT;         // 32 MiB + 64 (proven available)

  if (ws_size >= need) {
    unsigned char* p = (unsigned char*)d_ws;
    unsigned short* decTb = (unsigned short*)(p + 64);
    float* XT = (float*)(p + 64 + B_decT);
    float* WT = (float*)(p + 64 + B_decT + B_XT);
    k_transblk<<<dim3(BATCH / 32, IN_DIM / 32), 256, 0, stream>>>(x, XT);
    k_transblk<<<dim3(HID_DIM / 32, IN_DIM / 32), 256, 0, stream>>>(enc_w, WT);
    k_transb<<<dim3(HID_DIM / 32, OUT_DIM / 32), 256, 0, stream>>>(dec_w, decTb);
    k_gemm_pk2<<<dim3(HID_DIM / 128, BATCH / 128), 256, 0, stream>>>(XT, WT, enc_b, hid);
    k_topk3<<<dim3(BATCH), 256, 0, stream>>>(decTb, dec_b, kptr, out, hid);
  } else {
    k_gemm_pk<<<dim3(HID_DIM / 128, BATCH / 128), 256, 0, stream>>>(x, enc_w, enc_b, hid);
    k_topkf<<<dim3(BATCH), 256, 0, stream>>>(dec_w, dec_b, kptr, out, hid);
  }
}

// Round 13
// 1320.368 us; speedup vs baseline: 1.2283x; 1.2283x over previous
//
#include <hip/hip_runtime.h>
#include <stdint.h>

#define BATCH   8192
#define IN_DIM  256
#define HID_DIM 16384
#define OUT_DIM 256

#define SELCAPF 2048
#define BCAP    128

typedef __attribute__((ext_vector_type(8))) __bf16 bf16x8;
typedef __attribute__((ext_vector_type(4))) float  f32x4;
typedef __attribute__((ext_vector_type(2))) float  f32x2;
typedef __attribute__((ext_vector_type(8))) unsigned short u16x8;

__device__ __forceinline__ void load_lds_16B(const void* g, void* l) {
  __builtin_amdgcn_global_load_lds(
      (const __attribute__((address_space(1))) unsigned int*)g,
      (__attribute__((address_space(3))) unsigned int*)l, 16, 0, 0);
}
__device__ __forceinline__ float bf16u_to_f(unsigned short u) {
  return __uint_as_float(((unsigned)u) << 16);
}
__device__ __forceinline__ unsigned short f_to_bf16_rne(float f) {
  unsigned u = __float_as_uint(f);
  u += 0x7fffu + ((u >> 16) & 1u);
  return (unsigned short)(u >> 16);
}
__device__ __forceinline__ int read_k(const int* kptr) {
  int k = kptr[0];
  if (k <= 0 || k > 100000000) {
    float kf = __int_as_float(k);
    if (kf >= 1.f && kf <= 16384.f) k = (int)kf;
  }
  if (k < 1) k = 1;
  if (k > HID_DIM) k = HID_DIM;
  return k;
}
__device__ __forceinline__ f32x2 fma2(f32x2 a, f32x2 b, f32x2 c) {
#if __has_builtin(__builtin_elementwise_fma)
  return __builtin_elementwise_fma(a, b, c);
#else
  f32x2 r; r[0] = fmaf(a[0], b[0], c[0]); r[1] = fmaf(a[1], b[1], c[1]); return r;
#endif
}

// ---------------- split fp32 -> (hi bf16, lo bf16) planes (R4 verbatim) ----------------
__global__ __launch_bounds__(256) void k_split(const float* __restrict__ src,
                                               unsigned short* __restrict__ hi,
                                               unsigned short* __restrict__ lo,
                                               int n8) {
  const int i = blockIdx.x * 256 + threadIdx.x;
  if (i >= n8) return;
  const int base = i * 8;
  const f32x4 a = *(const f32x4*)&src[base];
  const f32x4 b = *(const f32x4*)&src[base + 4];
  u16x8 h, l;
#pragma unroll
  for (int e = 0; e < 4; e++) {
    { const float v = a[e]; const unsigned short hb = f_to_bf16_rne(v);
      h[e] = hb; l[e] = f_to_bf16_rne(v - bf16u_to_f(hb)); }
    { const float v = b[e]; const unsigned short hb = f_to_bf16_rne(v);
      h[e + 4] = hb; l[e + 4] = f_to_bf16_rne(v - bf16u_to_f(hb)); }
  }
  *(u16x8*)&hi[base] = h;
  *(u16x8*)&lo[base] = l;
}

// ---------------- dec_w (256 x 16384 fp32) -> dec_wT (16384 x 256 bf16) ----------------
__global__ __launch_bounds__(256) void k_transb(const float* __restrict__ dec_w,
                                                unsigned short* __restrict__ decT) {
  __shared__ float tile[32][33];
  int j0 = blockIdx.x * 32, o0 = blockIdx.y * 32;
  int tx = threadIdx.x & 31, ty = threadIdx.x >> 5;
#pragma unroll
  for (int rr = 0; rr < 4; rr++)
    tile[ty + rr * 8][tx] = dec_w[(size_t)(o0 + ty + rr * 8) * HID_DIM + (j0 + tx)];
  __syncthreads();
#pragma unroll
  for (int rr = 0; rr < 4; rr++)
    decT[(size_t)(j0 + ty + rr * 8) * OUT_DIM + (o0 + tx)] = f_to_bf16_rne(tile[tx][ty + rr * 8]);
}

// ---------------- GEMM1 (3xbf16 MFMA, R4 verbatim — values validated by R4/R5 output 0) -----
__global__ __launch_bounds__(256) void k_gemm3(const unsigned short* __restrict__ Xh,
                                               const unsigned short* __restrict__ Xl,
                                               const unsigned short* __restrict__ Wh,
                                               const unsigned short* __restrict__ Wl,
                                               const float* __restrict__ encb,
                                               float* __restrict__ hid) {
  __shared__ __align__(16) unsigned short Ash[128 * 64];
  __shared__ __align__(16) unsigned short Asl[128 * 64];
  __shared__ __align__(16) unsigned short Bsh[128 * 64];
  __shared__ __align__(16) unsigned short Bsl[128 * 64];

  const int bn = blockIdx.x, bm = blockIdx.y;
  const int t = threadIdx.x, w = t >> 6, lane = t & 63;
  const int wm = w >> 1, wn = w & 1;
  f32x4 acc[4][4] = {};

  const int lrow8 = lane >> 3;
  const int cblk  = (lane & 7) ^ lrow8;   // XOR swizzle on the gather side

  const size_t aoff = (size_t)(bm * 128) * IN_DIM;
  const size_t boff = (size_t)(bn * 128) * IN_DIM;

  for (int kb = 0; kb < 4; kb++) {        // K = 256, BK = 64
#pragma unroll
    for (int o = 0; o < 4; o++) {
      const int R = (w * 4 + o) * 8;
      const size_t go = (size_t)(R + lrow8) * IN_DIM + kb * 64 + cblk * 8;
      load_lds_16B(Xh + aoff + go, &Ash[(w * 4 + o) * 512]);
      load_lds_16B(Xl + aoff + go, &Asl[(w * 4 + o) * 512]);
      load_lds_16B(Wh + boff + go, &Bsh[(w * 4 + o) * 512]);
      load_lds_16B(Wl + boff + go, &Bsl[(w * 4 + o) * 512]);
    }
    __syncthreads();
#pragma unroll
    for (int ks = 0; ks < 2; ks++) {
      bf16x8 ah[4], al[4], bh[4], bl[4];
#pragma unroll
      for (int i = 0; i < 4; i++) {
        const int row = wm * 64 + i * 16 + (lane & 15);
        const int c   = (ks * 4 + (lane >> 4)) ^ (row & 7);
        ah[i] = *(const bf16x8*)&Ash[row * 64 + c * 8];
        al[i] = *(const bf16x8*)&Asl[row * 64 + c * 8];
      }
#pragma unroll
      for (int j = 0; j < 4; j++) {
        const int row = wn * 64 + j * 16 + (lane & 15);
        const int c   = (ks * 4 + (lane >> 4)) ^ (row & 7);
        bh[j] = *(const bf16x8*)&Bsh[row * 64 + c * 8];
        bl[j] = *(const bf16x8*)&Bsl[row * 64 + c * 8];
      }
#pragma unroll
      for (int i = 0; i < 4; i++)
#pragma unroll
        for (int j = 0; j < 4; j++) {
          acc[i][j] = __builtin_amdgcn_mfma_f32_16x16x32_bf16(al[i], bh[j], acc[i][j], 0, 0, 0);
          acc[i][j] = __builtin_amdgcn_mfma_f32_16x16x32_bf16(ah[i], bl[j], acc[i][j], 0, 0, 0);
          acc[i][j] = __builtin_amdgcn_mfma_f32_16x16x32_bf16(ah[i], bh[j], acc[i][j], 0, 0, 0);
        }
    }
    __syncthreads();
  }

#pragma unroll
  for (int j = 0; j < 4; j++) {
    const int gc = bn * 128 + wn * 64 + j * 16 + (lane & 15);
    const float eb = encb[gc];
#pragma unroll
    for (int i = 0; i < 4; i++) {
      const int gr0 = bm * 128 + wm * 64 + i * 16 + ((lane >> 4) << 2);
#pragma unroll
      for (int rg = 0; rg < 4; rg++) {
        float h = acc[i][j][rg] + eb;
        h = (h > 0.f) ? h : 0.f;
        hid[(size_t)(gr0 + rg) * HID_DIM + gc] = h;
      }
    }
  }
}

// ---------------- topk7: topk3 radix + borderline exact-chain recompute ----------------------
// T' = k-th largest stored (3xbf16) value via proven full 32-bit radix. Values with
// |v-T'| <= delta are recomputed with the BIT-EXACT fp32 ascending-k fmaf chain (the
// selection that matched numpy in R3/R6/R10); keep rule uses chain values at the boundary.
__global__ __launch_bounds__(256) void k_topk7(const float* __restrict__ X,
                                               const float* __restrict__ encw,
                                               const float* __restrict__ encb,
                                               const unsigned short* __restrict__ decTb,
                                               const float* __restrict__ decb,
                                               const int* __restrict__ kptr,
                                               float* __restrict__ out,
                                               float* __restrict__ hid) {
  __shared__ unsigned hist[8][257];
  __shared__ unsigned cums[257];
  __shared__ float xrow[IN_DIM];
  __shared__ int bidx[BCAP];
  __shared__ float chv[BCAP];
  __shared__ unsigned char bkeep[BCAP];
  __shared__ float selV[SELCAPF];
  __shared__ unsigned short selI[SELCAPF];
  __shared__ unsigned s_selcnt, s_b, s_need, s_bcnt, s_m;
  __shared__ float s_tau;
  __shared__ int s_keepall;

  const int r = blockIdx.x, t = threadIdx.x;
  float* hrow = hid + (size_t)r * HID_DIM;
  const int k = read_k(kptr);

  // Row -> registers (the ONLY global read of the row).
  f32x4 row[16];
#pragma unroll
  for (int c = 0; c < 16; c++) row[c] = *(const f32x4*)&hrow[(c * 256 + t) * 4];

  xrow[t] = X[(size_t)r * IN_DIM + t];
  for (int i = t; i < 8 * 257; i += 256) ((unsigned*)hist)[i] = 0u;
  if (t == 0) { s_selcnt = 0; s_keepall = 0; s_bcnt = 0; s_m = 0; s_tau = -1.f; }
  __syncthreads();

  // Radix pass 0: top byte (post-relu => sign bit 0); skip byte==0.
#pragma unroll
  for (int c = 0; c < 16; c++)
#pragma unroll
    for (int e = 0; e < 4; e++) {
      const unsigned b = __float_as_uint(row[c][e]) >> 24;
      if (b) atomicAdd(&hist[t & 7][b], 1u);
    }
  __syncthreads();
  { unsigned s = 0;
#pragma unroll
    for (int cpy = 0; cpy < 8; cpy++) s += hist[cpy][t];
    cums[t] = s; }
  __syncthreads();
  for (int off = 1; off < 256; off <<= 1) {
    const unsigned v = cums[t];
    const unsigned a = (t + off < 256) ? cums[t + off] : 0u;
    __syncthreads();
    cums[t] = v + a;
    __syncthreads();
  }
  if (t == 0 && cums[1] < (unsigned)k) s_keepall = 1;
  if (t >= 1) {
    const unsigned incl = cums[t], excl = (t < 255) ? cums[t + 1] : 0u;
    if (incl >= (unsigned)k && excl < (unsigned)k) { s_b = (unsigned)t; s_need = (unsigned)k - excl; }
  }
  __syncthreads();

  unsigned prefix = 0;
  const int keepall = s_keepall;
  if (!keepall) {
    prefix = s_b << 24;
    unsigned need = s_need;
    for (int pass = 0; pass < 3; pass++) {
      const int shift = 16 - pass * 8;
      for (int i = t; i < 8 * 257; i += 256) ((unsigned*)hist)[i] = 0u;
      __syncthreads();
      const unsigned pfx = prefix;
      const int pshift = shift + 8;
#pragma unroll
      for (int c = 0; c < 16; c++)
#pragma unroll
        for (int e = 0; e < 4; e++) {
          const unsigned bits = __float_as_uint(row[c][e]);
          if ((bits >> pshift) == (pfx >> pshift))
            atomicAdd(&hist[t & 7][(bits >> shift) & 255u], 1u);
        }
      __syncthreads();
      { unsigned s = 0;
#pragma unroll
        for (int cpy = 0; cpy < 8; cpy++) s += hist[cpy][t];
        cums[t] = s; }
      __syncthreads();
      for (int off = 1; off < 256; off <<= 1) {
        const unsigned v = cums[t];
        const unsigned a = (t + off < 256) ? cums[t + off] : 0u;
        __syncthreads();
        cums[t] = v + a;
        __syncthreads();
      }
      { const unsigned incl = cums[t], excl = (t < 255) ? cums[t + 1] : 0u;
        if (incl >= need && excl < need) { s_b = (unsigned)t; s_need = need - excl; } }
      __syncthreads();
      prefix |= s_b << shift;
      need = s_need;
      __syncthreads();
    }
  }
  const unsigned T = prefix;   // exact bits of k-th largest STORED value

  // Borderline band: |v - Tf| <= delta. Outside the band, stored-value classification is
  // provably identical to chain-value classification (|v_stored - v_chain| << delta).
  float wloB = 1.0f, whiB = -1.0f;
  int mode = keepall ? 0 : 2;            // 0=keepall, 1=plain bits>=T, 2=band
  if (!keepall) {
    const float Tf = __uint_as_float(T);
    const float delta = 1e-3f + Tf * 1e-3f;
    wloB = Tf - delta; whiB = Tf + delta;
    unsigned mloc = 0;
#pragma unroll
    for (int c = 0; c < 16; c++)
#pragma unroll
      for (int e = 0; e < 4; e++) {
        const float v = row[c][e];
        if (v > whiB) mloc++;
        else if (v >= wloB && v > 0.f) {
          const unsigned p = atomicAdd(&s_bcnt, 1u);
          if (p < BCAP) bidx[p] = (c * 256 + t) * 4 + e;
        }
      }
    if (mloc) atomicAdd(&s_m, mloc);
  }
  __syncthreads();
  const unsigned bcnt = s_bcnt;
  if (!keepall && (bcnt == 0 || bcnt > BCAP || wloB <= 0.f)) mode = 1;   // fallback: topk3 rule

  if (mode == 2) {
    // Exact chain recompute of borderline candidates (one per thread, serial ascending k —
    // bit-identical op sequence to the R3/R6/R10 gemm chain).
    if (t < (int)bcnt) {
      const int j = bidx[t];
      const float* wr = encw + (size_t)j * IN_DIM;
      float acc = 0.f;
      for (int kk = 0; kk < IN_DIM; kk += 8) {
        const f32x4 w0 = *(const f32x4*)&wr[kk];
        const f32x4 w1 = *(const f32x4*)&wr[kk + 4];
        acc = fmaf(xrow[kk + 0], w0[0], acc);
        acc = fmaf(xrow[kk + 1], w0[1], acc);
        acc = fmaf(xrow[kk + 2], w0[2], acc);
        acc = fmaf(xrow[kk + 3], w0[3], acc);
        acc = fmaf(xrow[kk + 4], w1[0], acc);
        acc = fmaf(xrow[kk + 5], w1[1], acc);
        acc = fmaf(xrow[kk + 6], w1[2], acc);
        acc = fmaf(xrow[kk + 7], w1[3], acc);
      }
      acc += encb[j];
      acc = (acc > 0.f) ? acc : 0.f;
      chv[t] = acc;
    }
    __syncthreads();
    const unsigned need = (unsigned)k - s_m;   // 1..bcnt guaranteed (see band proof)
    if (t < (int)bcnt) {
      const float v = chv[t];
      unsigned g = 0, e = 0;
      for (unsigned m2 = 0; m2 < bcnt; m2++) {
        const float u = chv[m2];
        g += (u > v); e += (u == v);
      }
      if (g < need && need <= g + e) s_tau = v;   // unique value; any writer same bits
    }
    __syncthreads();
    if (t < (int)bcnt) bkeep[t] = (chv[t] >= s_tau) ? 1 : 0;
    __syncthreads();
  }

  // Mask + write hidden_post + gather survivors (all from registers).
#pragma unroll
  for (int c = 0; c < 16; c++) {
    const int base = (c * 256 + t) * 4;
    f32x4 o;
#pragma unroll
    for (int e = 0; e < 4; e++) {
      const float v = row[c][e];
      const unsigned bits = __float_as_uint(v);
      bool keep;
      if (mode == 0) keep = true;
      else if (mode == 1) keep = (bits >= T);
      else {
        if (v > whiB) keep = true;
        else if (v < wloB || v <= 0.f) keep = false;
        else {
          keep = false;
          for (unsigned m2 = 0; m2 < bcnt; m2++)
            if (bidx[m2] == base + e) { keep = (bkeep[m2] != 0); break; }
        }
      }
      o[e] = keep ? v : 0.f;
      if (keep && bits != 0u) {
        const unsigned p = atomicAdd(&s_selcnt, 1u);
        if (p < SELCAPF) { selV[p] = v; selI[p] = (unsigned short)(base + e); }
      }
    }
    *(f32x4*)&hrow[base] = o;
  }
  __syncthreads();

  // Fused sparse decode: out[r][t] = dec_b[t] + sum_s v_s * dec_w[t][j_s]
  const unsigned nsel = s_selcnt;
  float a0 = decb[t], a1 = 0.f, a2 = 0.f, a3 = 0.f;
  if (nsel <= SELCAPF) {
    unsigned s = 0;
    for (; s + 4 <= nsel; s += 4) {
      a0 += selV[s + 0] * bf16u_to_f(decTb[(size_t)selI[s + 0] * OUT_DIM + t]);
      a1 += selV[s + 1] * bf16u_to_f(decTb[(size_t)selI[s + 1] * OUT_DIM + t]);
      a2 += selV[s + 2] * bf16u_to_f(decTb[(size_t)selI[s + 2] * OUT_DIM + t]);
      a3 += selV[s + 3] * bf16u_to_f(decTb[(size_t)selI[s + 3] * OUT_DIM + t]);
    }
    for (; s < nsel; s++)
      a0 += selV[s] * bf16u_to_f(decTb[(size_t)selI[s] * OUT_DIM + t]);
  } else {
    for (int j = 0; j < HID_DIM; j++) {
      const float hv = hrow[j];
      if (hv != 0.f) a0 += hv * bf16u_to_f(decTb[(size_t)j * OUT_DIM + t]);
    }
  }
  out[(size_t)r * OUT_DIM + t] = (a0 + a1) + (a2 + a3);
}

// ======================= fallback (small ws): R7's proven kernels =======================
__global__ __launch_bounds__(256, 4) void k_gemm_pk(const float* __restrict__ X,
                                                    const float* __restrict__ W,
                                                    const float* __restrict__ encb,
                                                    float* __restrict__ hid) {
  __shared__ float As[32][132];
  __shared__ float Bs[32][132];
  const int bn = blockIdx.x, bm = blockIdx.y;
  const int t = threadIdx.x;
  const int tx = t & 15, ty = t >> 4;
  const int sr = t & 127, sh = t >> 7;
  f32x2 acc[8][4] = {};
  const float* Ab = X + (size_t)(bm * 128) * IN_DIM;
  const float* Bb = W + (size_t)(bn * 128) * IN_DIM;
  for (int k0 = 0; k0 < IN_DIM; k0 += 32) {
#pragma unroll
    for (int q = 0; q < 4; q++) {
      const int ko = sh * 16 + q * 4;
      const float4 av = *(const float4*)&Ab[(size_t)sr * IN_DIM + k0 + ko];
      As[ko + 0][sr] = av.x; As[ko + 1][sr] = av.y;
      As[ko + 2][sr] = av.z; As[ko + 3][sr] = av.w;
      const float4 bv = *(const float4*)&Bb[(size_t)sr * IN_DIM + k0 + ko];
      Bs[ko + 0][sr] = bv.x; Bs[ko + 1][sr] = bv.y;
      Bs[ko + 2][sr] = bv.z; Bs[ko + 3][sr] = bv.w;
    }
    __syncthreads();
#pragma unroll 8
    for (int kk = 0; kk < 32; kk++) {
      const f32x4 av0 = *(const f32x4*)&As[kk][ty * 8];
      const f32x4 av1 = *(const f32x4*)&As[kk][ty * 8 + 4];
      const f32x4 bv0 = *(const f32x4*)&Bs[kk][tx * 8];
      const f32x4 bv1 = *(const f32x4*)&Bs[kk][tx * 8 + 4];
      f32x2 b2[4];
      b2[0] = __builtin_shufflevector(bv0, bv0, 0, 1);
      b2[1] = __builtin_shufflevector(bv0, bv0, 2, 3);
      b2[2] = __builtin_shufflevector(bv1, bv1, 0, 1);
      b2[3] = __builtin_shufflevector(bv1, bv1, 2, 3);
#pragma unroll
      for (int i = 0; i < 8; i++) {
        const float asc = (i < 4) ? av0[i & 3] : av1[i & 3];
        f32x2 ai; ai[0] = asc; ai[1] = asc;
#pragma unroll
        for (int j = 0; j < 4; j++) acc[i][j] = fma2(ai, b2[j], acc[i][j]);
      }
    }
    __syncthreads();
  }
#pragma unroll
  for (int i = 0; i < 8; i++) {
    const int m = bm * 128 + ty * 8 + i;
    float o[8];
#pragma unroll
    for (int j = 0; j < 4; j++) {
      const float h0 = acc[i][j][0] + encb[bn * 128 + tx * 8 + j * 2];
      const float h1 = acc[i][j][1] + encb[bn * 128 + tx * 8 + j * 2 + 1];
      o[j * 2] = (h0 > 0.f) ? h0 : 0.f;
      o[j * 2 + 1] = (h1 > 0.f) ? h1 : 0.f;
    }
    float* dst = &hid[(size_t)m * HID_DIM + bn * 128 + tx * 8];
    *(float4*)dst = *(float4*)&o[0];
    *(float4*)(dst + 4) = *(float4*)&o[4];
  }
}

__global__ __launch_bounds__(256) void k_topkf(const float* __restrict__ dec,
                                               const float* __restrict__ decb,
                                               const int* __restrict__ kptr,
                                               float* __restrict__ out,
                                               float* __restrict__ hid) {
  __shared__ unsigned hist[8][257];
  __shared__ unsigned tot[256];
  __shared__ float selV[SELCAPF];
  __shared__ unsigned short selI[SELCAPF];
  __shared__ unsigned s_selcnt, s_need, s_pref, s_byte;
  __shared__ int s_keepall;
  const int r = blockIdx.x, t = threadIdx.x;
  float* hrow = hid + (size_t)r * HID_DIM;
  const int k = read_k(kptr);
  for (int i = t; i < 8 * 257; i += 256) ((unsigned*)hist)[i] = 0u;
  if (t == 0) { s_selcnt = 0; s_keepall = 0; s_pref = 0; }
  __syncthreads();
#pragma unroll
  for (int c = 0; c < 16; c++) {
    const f32x4 v = *(const f32x4*)&hrow[(c * 256 + t) * 4];
#pragma unroll
    for (int e = 0; e < 4; e++) {
      const unsigned b = __float_as_uint(v[e]) >> 24;
      if (b) atomicAdd(&hist[t & 7][b], 1u);
    }
  }
  __syncthreads();
  { unsigned s = 0;
#pragma unroll
    for (int c = 0; c < 8; c++) s += hist[c][t];
    tot[t] = s; }
  __syncthreads();
  if (t == 0) {
    unsigned cum = 0; int b1 = -1; unsigned need = 0;
    for (int b = 255; b >= 1; b--) {
      const unsigned c = tot[b];
      if (cum + c >= (unsigned)k) { b1 = b; need = (unsigned)k - cum; break; }
      cum += c;
    }
    if (b1 < 0) s_keepall = 1;
    else { s_pref = ((unsigned)b1) << 24; s_need = need; }
  }
  __syncthreads();
  if (!s_keepall) {
    for (int pass = 1; pass <= 3; pass++) {
      const int shift = 24 - pass * 8;
      tot[t] = 0;
      __syncthreads();
      const unsigned prefhi = s_pref >> (shift + 8);
#pragma unroll
      for (int c = 0; c < 16; c++) {
        const f32x4 v = *(const f32x4*)&hrow[(c * 256 + t) * 4];
#pragma unroll
        for (int e = 0; e < 4; e++) {
          const unsigned bits = __float_as_uint(v[e]);
          if ((bits >> (shift + 8)) == prefhi) atomicAdd(&tot[(bits >> shift) & 255u], 1u);
        }
      }
      __syncthreads();
      if (t == 0) {
        unsigned cum = 0; const unsigned need = s_need;
        for (int b = 255; b >= 0; b--) {
          const unsigned c = tot[b];
          if (cum + c >= need) { s_byte = (unsigned)b; s_need = need - cum; break; }
          cum += c;
        }
        s_pref |= s_byte << shift;
      }
      __syncthreads();
    }
  }
  const int keepall = s_keepall;
  const unsigned T = s_pref;
#pragma unroll
  for (int c = 0; c < 16; c++) {
    const int base = (c * 256 + t) * 4;
    const f32x4 v = *(const f32x4*)&hrow[base];
    f32x4 o;
#pragma unroll
    for (int e = 0; e < 4; e++) {
      const unsigned bits = __float_as_uint(v[e]);
      const bool keep = keepall || (bits >= T);
      o[e] = keep ? v[e] : 0.f;
      if (keep && bits != 0u) {
        const unsigned p = atomicAdd(&s_selcnt, 1u);
        if (p < SELCAPF) { selV[p] = v[e]; selI[p] = (unsigned short)(base + e); }
      }
    }
    *(f32x4*)&hrow[base] = o;
  }
  __syncthreads();
  const unsigned nsel = s_selcnt;
  float a0 = decb[t], a1 = 0.f, a2 = 0.f, a3 = 0.f;
  if (nsel <= SELCAPF) {
    unsigned s = 0;
    for (; s + 4 <= nsel; s += 4) {
#pragma unroll
      for (int u = 0; u < 4; u++) {
        const unsigned idx = selI[s + u];
        (u == 0 ? a0 : u == 1 ? a1 : u == 2 ? a2 : a3) += selV[s + u] * dec[(size_t)t * HID_DIM + idx];
      }
    }
    for (; s < nsel; s++)
      a0 += selV[s] * dec[(size_t)t * HID_DIM + selI[s]];
  } else {
    for (int j = 0; j < HID_DIM; j++) {
      const float hv = hrow[j];
      if (hv != 0.f) a0 += hv * dec[(size_t)t * HID_DIM + j];
    }
  }
  out[(size_t)r * OUT_DIM + t] = (a0 + a1) + (a2 + a3);
}

extern "C" void kernel_launch(void* const* d_in, const int* in_sizes, int n_in,
                              void* d_out, int out_size, void* d_ws, size_t ws_size,
                              hipStream_t stream) {
  // Order remap (dict vs alphabetical), by size signature — proven in R3-R12.
  int ix = 0, iew = 1, ieb = 2, idw = 3, idb = 4, ik = 5;
  if (n_in >= 6 && in_sizes[0] == OUT_DIM && in_sizes[5] == BATCH * IN_DIM) {
    idb = 0; idw = 1; ieb = 2; iew = 3; ik = 4; ix = 5;
  }
  const float* x     = (const float*)d_in[ix];
  const float* enc_w = (const float*)d_in[iew];
  const float* enc_b = (const float*)d_in[ieb];
  const float* dec_w = (const float*)d_in[idw];
  const float* dec_b = (const float*)d_in[idb];
  const int*   kptr  = (const int*)d_in[ik];

  float* out = (float*)d_out;
  float* hid = out + (size_t)BATCH * OUT_DIM;

  const size_t B_decT = (size_t)HID_DIM * OUT_DIM * 2;   // 8 MiB
  const size_t B_xpl  = (size_t)BATCH * IN_DIM * 2;      // 4 MiB per plane
  const size_t B_wpl  = (size_t)HID_DIM * IN_DIM * 2;    // 8 MiB per plane
  const size_t need = 64 + B_decT + 2 * B_xpl + 2 * B_wpl;   // 32 MiB + 64 (proven available)

  if (ws_size >= need) {
    unsigned char* p = (unsigned char*)d_ws;
    unsigned short* decTb = (unsigned short*)(p + 64);
    unsigned short* xhi = (unsigned short*)(p + 64 + B_decT);
    unsigned short* xlo = (unsigned short*)(p + 64 + B_decT + B_xpl);
    unsigned short* wHi = (unsigned short*)(p + 64 + B_decT + 2 * B_xpl);
    unsigned short* wLo = (unsigned short*)(p + 64 + B_decT + 2 * B_xpl + B_wpl);

    k_split<<<dim3((BATCH * IN_DIM / 8 + 255) / 256), 256, 0, stream>>>(x, xhi, xlo, BATCH * IN_DIM / 8);
    k_split<<<dim3((HID_DIM * IN_DIM / 8 + 255) / 256), 256, 0, stream>>>(enc_w, wHi, wLo, HID_DIM * IN_DIM / 8);
    k_transb<<<dim3(HID_DIM / 32, OUT_DIM / 32), 256, 0, stream>>>(dec_w, decTb);
    k_gemm3<<<dim3(HID_DIM / 128, BATCH / 128), 256, 0, stream>>>(xhi, xlo, wHi, wLo, enc_b, hid);
    k_topk7<<<dim3(BATCH), 256, 0, stream>>>(x, enc_w, enc_b, decTb, dec_b, kptr, out, hid);
  } else {
    k_gemm_pk<<<dim3(HID_DIM / 128, BATCH / 128), 256, 0, stream>>>(x, enc_w, enc_b, hid);
    k_topkf<<<dim3(BATCH), 256, 0, stream>>>(dec_w, dec_b, kptr, out, hid);
  }
}